// Round 8
// baseline (353.509 us; speedup 1.0000x reference)
//
#include <hip/hip_runtime.h>
#include <hip/hip_bf16.h>
#include <math.h>

// Problem constants
#define MM 12544   // 64 * 196 patches (M)
#define KK 768     // 16*16*3 (K)
#define NN 768     // embedding dim (N)
#define KS 24      // k-steps of 32
#define NF 48      // n-tiles of 16
#define NWAVES (MM / 16)   // 784 single-wave blocks

typedef __bf16 v8bf __attribute__((ext_vector_type(8)));
typedef float  v4f  __attribute__((ext_vector_type(4)));

// ---------------------------------------------------------------------------
// W-pack in MFMA-B-fragment-direct order:
// frag(s,t) = 1 KB at ((s*48+t)*64 + lane)*16 bytes, lane holds 8 bf16 =
// W[k = s*32 + (lane>>4)*8 + j][n = t*16 + (lane&15)], j=0..7.
// The GEMM then loads B-frags with a single per-lane global_load_dwordx4.
// ---------------------------------------------------------------------------
__global__ __launch_bounds__(256) void wt_pack(const float* __restrict__ w,
                                               __hip_bfloat16* __restrict__ wpack) {
    int tid = blockIdx.x * 256 + threadIdx.x;   // 0 .. 24*48*64-1 = 73727
    int l   = tid & 63;
    int ft  = (tid >> 6) % NF;    // n-tile
    int s   = (tid >> 6) / NF;    // k-step
    int n   = ft * 16 + (l & 15);
    int k   = s * 32 + (l >> 4) * 8;
    float f[8];
#pragma unroll
    for (int j = 0; j < 8; j++) f[j] = w[(size_t)(k + j) * NN + n];
    union { __hip_bfloat16 h[8]; uint4 u; } o;
#pragma unroll
    for (int j = 0; j < 8; j++) o.h[j] = __float2bfloat16(f[j]);
    *(uint4*)(wpack + (size_t)tid * 8) = o.u;
}

// Fast GELU: x*E/(E+1), E=e^{2t}, t=0.79788456(x+0.044715x^3).
__device__ __forceinline__ float gelu_fast(float x) {
    float t2 = 1.5957691216057308f * x * (1.0f + 0.044715f * x * x);
    float e  = __expf(t2);
    float r  = __builtin_amdgcn_rcpf(e + 1.0f);
    return x - x * r;
}

// ---------------------------------------------------------------------------
// Barrier-free fused im2col GEMM: one wave owns a 16-row x 768-col strip.
// No LDS, no __syncthreads — nothing to drain. Per k-step: A-frag direct
// from image (2x float4 + cvt, in registers), 48 B-frags via per-lane
// dwordx4 from L2-resident wpack, 48 MFMAs. Compiler pipelines with
// fine-grained vmcnt (its strength; only barriers force vmcnt(0)).
// acc = 48 x v4f = 192 VGPR; launch_bounds(64,1) -> 512 VGPR budget.
// ---------------------------------------------------------------------------
__global__ __launch_bounds__(64, 1) void gemm_gelu(const float* __restrict__ img,
                                                   const __hip_bfloat16* __restrict__ wpack,
                                                   const float* __restrict__ bias,
                                                   float* __restrict__ out) {
    const int wid  = blockIdx.x;        // 0..783 -> rows [wid*16, wid*16+16)
    const int lane = threadIdx.x;       // 0..63
    const int col  = lane & 15;
    const int quad = lane >> 4;

    // --- per-lane im2col geometry: this lane's A-row ---
    unsigned m  = (unsigned)(wid * 16 + col);
    unsigned b  = m / 196u;
    unsigned pm = m - b * 196u;
    unsigned pr = pm / 14u;
    unsigned pc = pm - pr * 14u;
    const float* pbase = img + (size_t)(((b * 224u + pr * 16u) * 224u + pc * 16u) * 3u);

    v4f acc[NF];
    const v4f vzero = {0.f, 0.f, 0.f, 0.f};
#pragma unroll
    for (int t = 0; t < NF; t++) acc[t] = vzero;

    // --- prefetch A for s=0: k = quad*8 -> u = quad, i = u/6, rem = (u%6)*8 ---
    float4 c0, c1;
    {
        unsigned u   = (unsigned)quad;
        unsigned i   = u / 6u;
        unsigned rem = (u - i * 6u) * 8u;
        const float* p = pbase + i * 672u + rem;
        c0 = *(const float4*)p;
        c1 = *(const float4*)(p + 4);
    }

    const char* wl = (const char*)wpack + (size_t)lane * 16;   // lane base

    for (int s = 0; s < KS; s++) {
        // cvt current A loads -> bf16 fragment
        union { __hip_bfloat16 h[8]; v8bf v; } af;
        af.h[0] = __float2bfloat16(c0.x); af.h[1] = __float2bfloat16(c0.y);
        af.h[2] = __float2bfloat16(c0.z); af.h[3] = __float2bfloat16(c0.w);
        af.h[4] = __float2bfloat16(c1.x); af.h[5] = __float2bfloat16(c1.y);
        af.h[6] = __float2bfloat16(c1.z); af.h[7] = __float2bfloat16(c1.w);

        // prefetch A for s+1 (issued before the MFMA block; no waits here)
        if (s + 1 < KS) {
            unsigned u   = (unsigned)(4 * (s + 1) + quad);   // 0..95
            unsigned i   = u / 6u;
            unsigned rem = (u - i * 6u) * 8u;
            const float* p = pbase + i * 672u + rem;
            c0 = *(const float4*)p;
            c1 = *(const float4*)(p + 4);
        }

        // 48 B-frag loads + 48 MFMAs; independent acc chains
        const char* wf = wl + (size_t)s * NF * 1024;
#pragma unroll
        for (int t = 0; t < NF; t++) {
            v8bf bf = *(const v8bf*)(wf + (size_t)t * 1024);
            acc[t] = __builtin_amdgcn_mfma_f32_16x16x32_bf16(af.v, bf, acc[t], 0, 0, 0);
        }
    }

    // ---- epilogue: bias + fast GELU ----
    // C/D layout: col(n) = lane&15, row(m) = quad*4 + rg.
    float* orow = out + ((size_t)(wid * 16 + quad * 4)) * NN + col;
#pragma unroll
    for (int t = 0; t < NF; t++) {
        float bv = bias[t * 16 + col];
#pragma unroll
        for (int rg = 0; rg < 4; rg++) {
            float x = acc[t][rg] + bv;
            orow[(size_t)rg * NN + t * 16] = gelu_fast(x);
        }
    }
}

extern "C" void kernel_launch(void* const* d_in, const int* in_sizes, int n_in,
                              void* d_out, int out_size, void* d_ws, size_t ws_size,
                              hipStream_t stream) {
    const float* img   = (const float*)d_in[0];   // [64,224,224,3]
    const float* wproj = (const float*)d_in[1];   // [768,768]
    const float* bias  = (const float*)d_in[2];   // [768]
    float* out = (float*)d_out;                   // [64,196,768]

    __hip_bfloat16* wpack = (__hip_bfloat16*)d_ws;   // 1,179,648 B used

    wt_pack<<<dim3((KS * NF * 64) / 256), dim3(256), 0, stream>>>(wproj, wpack);
    gemm_gelu<<<dim3(NWAVES), dim3(64), 0, stream>>>(img, wpack, bias, out);
}